// Round 22
// baseline (24.314 us; speedup 1.0000x reference)
//
#include <hip/hip_runtime.h>

#define DD 128
#define NTC 8              // 8 col-tiles of 128 -> Cpad = 1024
#define NCOPY 8            // B replicas (one per XCD under round-robin)
#define COPYBYTES (NTC * 16384)   // 128 KB per replica
#define BM 64              // rows per block -> grid 512, 4 blocks/CU

typedef __attribute__((ext_vector_type(4))) float f32x4;
typedef long long i64;
typedef __attribute__((ext_vector_type(2))) long long i64x2;

__device__ __forceinline__ unsigned pk8(float a, float b, float c, float d) {
    int v = __builtin_amdgcn_cvt_pk_fp8_f32(a, b, 0, false);
    v = __builtin_amdgcn_cvt_pk_fp8_f32(c, d, v, true);
    return (unsigned)v;
}

// ---------- prep: centers -> fp8, WAVE-FRAGMENT order, 8 replicas + csq x8 ----------
// addr = nt*16384 + wcg*4096 + ks*1024 + lh*256 + li*16 + half*8
//   col = nt*128 + wcg*32 + half*16 + li ; dims = 32*ks + 8*lh .. +7
// wave wc lane l reads one dwordx4 at wc*4096 + l*16 (+nt*16384 +ks*1024).
__global__ void prep_centers(const float* __restrict__ ctr,
                             unsigned char* __restrict__ wsB,
                             float* __restrict__ csqh, int C, int Cpad) {
    int gid = blockIdx.x * 256 + threadIdx.x;
    int col = gid >> 4, q = (gid >> 2) & 3, cpg = gid & 3;
    if (col >= Cpad) return;
    const float* src = ctr + (size_t)col * DD + q * 32;
    const int colr = col & 127;
    const int wcg = colr >> 5, rem = colr & 31;
    const int half = rem >> 4, li_ = rem & 15;
    const unsigned fbase = (unsigned)(col >> 7) * 16384u + (unsigned)wcg * 4096u +
                           (unsigned)q * 1024u + (unsigned)li_ * 16u + (unsigned)half * 8u;
    float cs = 0.f;
    uint2 uu[4];
    #pragma unroll
    for (int m = 0; m < 4; ++m) {
        float4 v0 = make_float4(0.f,0.f,0.f,0.f), v1 = v0;
        if (col < C) {
            v0 = *(const float4*)(src + m * 8);
            v1 = *(const float4*)(src + m * 8 + 4);
        }
        cs = fmaf(v0.x,v0.x,cs); cs = fmaf(v0.y,v0.y,cs);
        cs = fmaf(v0.z,v0.z,cs); cs = fmaf(v0.w,v0.w,cs);
        cs = fmaf(v1.x,v1.x,cs); cs = fmaf(v1.y,v1.y,cs);
        cs = fmaf(v1.z,v1.z,cs); cs = fmaf(v1.w,v1.w,cs);
        uu[m].x = pk8(v0.x, v0.y, v0.z, v0.w);
        uu[m].y = pk8(v1.x, v1.y, v1.z, v1.w);
    }
    unsigned char* dst0 = wsB + (unsigned)(2*cpg)   * (unsigned)COPYBYTES + fbase;
    unsigned char* dst1 = wsB + (unsigned)(2*cpg+1) * (unsigned)COPYBYTES + fbase;
    #pragma unroll
    for (int m = 0; m < 4; ++m) {
        *(uint2*)(dst0 + (unsigned)m * 256u) = uu[m];
        *(uint2*)(dst1 + (unsigned)m * 256u) = uu[m];
    }
    cs += __shfl_xor(cs, 4); cs += __shfl_xor(cs, 8);
    if (q == 0) {
        float v = (col < C) ? 0.5f * cs : 1e30f;
        csqh[(2*cpg)   * 1024 + col] = v;
        csqh[(2*cpg+1) * 1024 + col] = v;
    }
}

// ---------- main: 64 rows/block, 256 thr, 4 blocks/CU; barrier-free bounded K-loop ----------
__global__ __launch_bounds__(256, 4) void center_mfma(
    const float* __restrict__ emb, const int* __restrict__ tgt,
    const float* __restrict__ ctr, const unsigned char* __restrict__ wsB,
    const float* __restrict__ csqh, float* __restrict__ partials)
{
    __shared__ uint4 sA4[512];    // 8 KB: 64 rows fp8, swizzled (A only)
    __shared__ float sRT[BM];
    __shared__ float sRed[4];
    unsigned char* sAb = (unsigned char*)sA4;

    const int t = threadIdx.x;
    const int row0 = blockIdx.x * BM;
    const int cp = blockIdx.x & (NCOPY - 1);
    const unsigned char* wsBx = wsB + (size_t)cp * COPYBYTES;
    const float* csqx = csqh + cp * 1024;

    const int l  = t & 63;
    const int wc = t >> 6;        // wave = col quarter (32 cols per tile)
    const int li = l & 15;
    const int lh = l >> 4;        // 0..3
    const unsigned sw = (unsigned)li << 3;

    // ---- A loads (4 thr/row, 32 dims each) + tgt ----
    const int r = t >> 2, q = t & 3;
    const float* srcE = emb + (size_t)(row0 + r) * DD + q * 32;
    const int y = tgt[row0 + r];
    const float* srcC = ctr + (size_t)y * DD + q * 32;
    float4 ev[8], cv[8];
    #pragma unroll
    for (int m = 0; m < 8; ++m) ev[m] = *(const float4*)(srcE + m * 4);
    #pragma unroll
    for (int m = 0; m < 8; ++m) cv[m] = *(const float4*)(srcC + m * 4);

    // ---- A-pack: rt_half + fp8 + swizzled LDS write ----
    {
        const unsigned swA = ((unsigned)r & 15u) << 3;
        float se = 0.f, sd = 0.f;
        #pragma unroll
        for (int m = 0; m < 4; ++m) {
            float4 e0 = ev[2*m], e1 = ev[2*m+1], c0 = cv[2*m], c1 = cv[2*m+1];
            se = fmaf(e0.x,e0.x,se); se = fmaf(e0.y,e0.y,se);
            se = fmaf(e0.z,e0.z,se); se = fmaf(e0.w,e0.w,se);
            se = fmaf(e1.x,e1.x,se); se = fmaf(e1.y,e1.y,se);
            se = fmaf(e1.z,e1.z,se); se = fmaf(e1.w,e1.w,se);
            float d;
            d = e0.x-c0.x; sd = fmaf(d,d,sd);  d = e0.y-c0.y; sd = fmaf(d,d,sd);
            d = e0.z-c0.z; sd = fmaf(d,d,sd);  d = e0.w-c0.w; sd = fmaf(d,d,sd);
            d = e1.x-c1.x; sd = fmaf(d,d,sd);  d = e1.y-c1.y; sd = fmaf(d,d,sd);
            d = e1.z-c1.z; sd = fmaf(d,d,sd);  d = e1.w-c1.w; sd = fmaf(d,d,sd);
            uint2 u;
            u.x = pk8(e0.x, e0.y, e0.z, e0.w);
            u.y = pk8(e1.x, e1.y, e1.z, e1.w);
            *(uint2*)(sAb + (unsigned)r * 128u +
                      ((8u * (unsigned)(q * 4 + m)) ^ swA)) = u;
        }
        se += __shfl_xor(se, 1); se += __shfl_xor(se, 2);
        sd += __shfl_xor(sd, 1); sd += __shfl_xor(sd, 2);
        if (q == 0) sRT[r] = 0.5f * (1.0f + sd - se);
    }
    __syncthreads();   // the ONLY barrier before the reduction

    // hoist A fragments: row = 16*mf + li; k = 8*lh + 32*ks + e
    i64 aF[4][4];
    #pragma unroll
    for (int mf = 0; mf < 4; ++mf)
        #pragma unroll
        for (int ks = 0; ks < 4; ++ks)
            aF[mf][ks] = *(const i64*)(sAb + (unsigned)(16*mf + li) * 128u +
                                       (((unsigned)(8*lh + 32*ks)) ^ sw));
    float rtv[16];
    #pragma unroll
    for (int mf = 0; mf < 4; ++mf)
        #pragma unroll
        for (int rr = 0; rr < 4; ++rr)
            rtv[mf*4+rr] = sRT[16*mf + 4*lh + rr];

    // per-lane B base: wave-fragment-ordered replica (coalesced dwordx4 per wave)
    const unsigned char* gB = wsBx + (unsigned)wc * 4096u + (unsigned)l * 16u;

    float tsum = 0.f;

    // ---- K-loop: barrier-free, unroll 1 (bounds register pressure) ----
    #pragma unroll 1
    for (int nt = 0; nt < NTC; ++nt) {
        const float cq0 = csqx[nt*128 + wc*32 + li];
        const float cq1 = csqx[nt*128 + wc*32 + 16 + li];

        i64 bF0[4], bF1[4];
        #pragma unroll
        for (int ks = 0; ks < 4; ++ks) {
            i64x2 v = *(const i64x2*)(gB + (unsigned)nt * 16384u + (unsigned)ks * 1024u);
            bF0[ks] = v.x;   // col wc*32 + li
            bF1[ks] = v.y;   // col wc*32 + 16 + li
        }

        f32x4 acc[4][2];
        #pragma unroll
        for (int mf = 0; mf < 4; ++mf)
            #pragma unroll
            for (int rr = 0; rr < 4; ++rr) {
                acc[mf][0][rr] = rtv[mf*4+rr];
                acc[mf][1][rr] = rtv[mf*4+rr];
            }

        #pragma unroll
        for (int ks = 0; ks < 4; ++ks)
            #pragma unroll
            for (int mf = 0; mf < 4; ++mf) {
                acc[mf][0] = __builtin_amdgcn_mfma_f32_16x16x32_fp8_fp8(aF[mf][ks], bF0[ks], acc[mf][0], 0, 0, 0);
                acc[mf][1] = __builtin_amdgcn_mfma_f32_16x16x32_fp8_fp8(aF[mf][ks], bF1[ks], acc[mf][1], 0, 0, 0);
            }

        float s0 = 0.f, s1 = 0.f;
        #pragma unroll
        for (int mf = 0; mf < 4; ++mf)
            #pragma unroll
            for (int rr = 0; rr < 4; ++rr) {
                s0 = fmaf(2.0f, fmaxf(acc[mf][0][rr] - cq0, 0.f), s0);
                s1 = fmaf(2.0f, fmaxf(acc[mf][1][rr] - cq1, 0.f), s1);
            }
        tsum += s0 + s1;
    }

    // ---- block reduction -> deterministic per-block partial ----
    float s = tsum;
    #pragma unroll
    for (int off = 32; off; off >>= 1) s += __shfl_down(s, off);
    if (l == 0) sRed[wc] = s;
    __syncthreads();
    if (t == 0) partials[blockIdx.x] = sRed[0] + sRed[1] + sRed[2] + sRed[3];
}

// ---------- final reduction ----------
__global__ void reduce_k(const float* __restrict__ partials, int n,
                         float* __restrict__ out, double diagSub, double invDenom) {
    __shared__ double sRed[4];
    int t = threadIdx.x;
    double s = 0.0;
    for (int i = t; i < n; i += 256) s += (double)partials[i];
    #pragma unroll
    for (int off = 32; off; off >>= 1) s += __shfl_down(s, off);
    if ((t & 63) == 0) sRed[t >> 6] = s;
    __syncthreads();
    if (t == 0) out[0] = (float)(((sRed[0]+sRed[1]+sRed[2]+sRed[3]) - diagSub) * invDenom);
}

extern "C" void kernel_launch(void* const* d_in, const int* in_sizes, int n_in,
                              void* d_out, int out_size, void* d_ws, size_t ws_size,
                              hipStream_t stream) {
    const float* emb = (const float*)d_in[0];
    const int*   tgt = (const int*)d_in[1];
    const float* ctr = (const float*)d_in[2];

    const int B = in_sizes[1];                 // 32768
    const int C = in_sizes[2] / DD;            // 1000
    const int Cpad = NTC * 128;                // 1024
    const int nblk = B / BM;                   // 512 = 4 blocks/CU (pairs of XCD share)

    unsigned char* wsB = (unsigned char*)d_ws;                        // 8 x 128 KB replicas
    float* csqh = (float*)(wsB + (size_t)NCOPY * COPYBYTES);          // 8 x 1024
    float* partials = csqh + NCOPY * 1024;                            // [nblk]

    prep_centers<<<(Cpad * 16) / 256, 256, 0, stream>>>(ctr, wsB, csqh, C, Cpad);
    center_mfma<<<nblk, 256, 0, stream>>>(emb, tgt, ctr, wsB, csqh, partials);
    reduce_k<<<1, 256, 0, stream>>>(partials, nblk, (float*)d_out,
                                    (double)B,
                                    1.0 / ((double)B * (double)(C - 1)));
}

// Round 23
// 22.124 us; speedup vs baseline: 1.0990x; 1.0990x over previous
//
#include <hip/hip_runtime.h>

#define DD 128
#define NTC 8              // 8 col-tiles of 128 -> Cpad = 1024
#define NCOPY 8            // B replicas (one per XCD under round-robin)
#define COPYBYTES (NTC * 16384)   // 128 KB per replica
#define BM 32              // rows per block -> grid 1024, 4 blocks/CU

typedef __attribute__((ext_vector_type(4))) float f32x4;
typedef long long i64;
typedef __attribute__((ext_vector_type(2))) long long i64x2;

__device__ __forceinline__ unsigned pk8(float a, float b, float c, float d) {
    int v = __builtin_amdgcn_cvt_pk_fp8_f32(a, b, 0, false);
    v = __builtin_amdgcn_cvt_pk_fp8_f32(c, d, v, true);
    return (unsigned)v;
}

// ---------- prep: centers -> fp8, WAVE-FRAGMENT order, 8 replicas + csq x8 ----------
// addr = nt*16384 + wcg*4096 + ks*1024 + lh*256 + li*16 + half*8
//   col = nt*128 + wcg*32 + half*16 + li ; dims = 32*ks + 8*lh .. +7
// wave wc lane l reads one dwordx4 at wc*4096 + l*16 (+nt*16384 +ks*1024).
__global__ void prep_centers(const float* __restrict__ ctr,
                             unsigned char* __restrict__ wsB,
                             float* __restrict__ csqh, int C, int Cpad) {
    int gid = blockIdx.x * 256 + threadIdx.x;
    int col = gid >> 4, q = (gid >> 2) & 3, cpg = gid & 3;
    if (col >= Cpad) return;
    const float* src = ctr + (size_t)col * DD + q * 32;
    const int colr = col & 127;
    const int wcg = colr >> 5, rem = colr & 31;
    const int half = rem >> 4, li_ = rem & 15;
    const unsigned fbase = (unsigned)(col >> 7) * 16384u + (unsigned)wcg * 4096u +
                           (unsigned)q * 1024u + (unsigned)li_ * 16u + (unsigned)half * 8u;
    float cs = 0.f;
    uint2 uu[4];
    #pragma unroll
    for (int m = 0; m < 4; ++m) {
        float4 v0 = make_float4(0.f,0.f,0.f,0.f), v1 = v0;
        if (col < C) {
            v0 = *(const float4*)(src + m * 8);
            v1 = *(const float4*)(src + m * 8 + 4);
        }
        cs = fmaf(v0.x,v0.x,cs); cs = fmaf(v0.y,v0.y,cs);
        cs = fmaf(v0.z,v0.z,cs); cs = fmaf(v0.w,v0.w,cs);
        cs = fmaf(v1.x,v1.x,cs); cs = fmaf(v1.y,v1.y,cs);
        cs = fmaf(v1.z,v1.z,cs); cs = fmaf(v1.w,v1.w,cs);
        uu[m].x = pk8(v0.x, v0.y, v0.z, v0.w);
        uu[m].y = pk8(v1.x, v1.y, v1.z, v1.w);
    }
    unsigned char* dst0 = wsB + (unsigned)(2*cpg)   * (unsigned)COPYBYTES + fbase;
    unsigned char* dst1 = wsB + (unsigned)(2*cpg+1) * (unsigned)COPYBYTES + fbase;
    #pragma unroll
    for (int m = 0; m < 4; ++m) {
        *(uint2*)(dst0 + (unsigned)m * 256u) = uu[m];
        *(uint2*)(dst1 + (unsigned)m * 256u) = uu[m];
    }
    cs += __shfl_xor(cs, 4); cs += __shfl_xor(cs, 8);
    if (q == 0) {
        float v = (col < C) ? 0.5f * cs : 1e30f;
        csqh[(2*cpg)   * 1024 + col] = v;
        csqh[(2*cpg+1) * 1024 + col] = v;
    }
}

// ---------- main: 32 rows/block, 256 thr, 4 blocks/CU; barrier-free BOUNDED K-loop ----------
__global__ __launch_bounds__(256, 4) void center_mfma(
    const float* __restrict__ emb, const int* __restrict__ tgt,
    const float* __restrict__ ctr, const unsigned char* __restrict__ wsB,
    const float* __restrict__ csqh, float* __restrict__ partials)
{
    __shared__ uint4 sA4[256];    // 4 KB: 32 rows fp8, swizzled (A only)
    __shared__ float sRT[BM];
    __shared__ float sRed[4];
    unsigned char* sAb = (unsigned char*)sA4;

    const int t = threadIdx.x;
    const int row0 = blockIdx.x * BM;
    const int cp = blockIdx.x & (NCOPY - 1);
    const unsigned char* wsBx = wsB + (size_t)cp * COPYBYTES;
    const float* csqx = csqh + cp * 1024;

    const int l  = t & 63;
    const int wc = t >> 6;        // wave = col quarter (32 cols per tile)
    const int li = l & 15;
    const int lh = l >> 4;        // 0..3
    const unsigned sw = (unsigned)li << 3;

    // ---- A loads (8 thr/row, 16 dims) + tgt ----
    const int r = t >> 3, q8 = t & 7;
    const float* srcE = emb + (size_t)(row0 + r) * DD + q8 * 16;
    const int y = tgt[row0 + r];
    const float* srcC = ctr + (size_t)y * DD + q8 * 16;
    float4 ev[4], cv[4];
    #pragma unroll
    for (int m = 0; m < 4; ++m) ev[m] = *(const float4*)(srcE + m * 4);
    #pragma unroll
    for (int m = 0; m < 4; ++m) cv[m] = *(const float4*)(srcC + m * 4);

    // ---- A-pack: rt_half + fp8 + swizzled LDS write ----
    {
        const unsigned swA = ((unsigned)r & 15u) << 3;
        float se = 0.f, sd = 0.f;
        #pragma unroll
        for (int m = 0; m < 4; ++m) {
            float4 e0 = ev[m], c0 = cv[m];
            se = fmaf(e0.x,e0.x,se); se = fmaf(e0.y,e0.y,se);
            se = fmaf(e0.z,e0.z,se); se = fmaf(e0.w,e0.w,se);
            float d;
            d = e0.x-c0.x; sd = fmaf(d,d,sd);  d = e0.y-c0.y; sd = fmaf(d,d,sd);
            d = e0.z-c0.z; sd = fmaf(d,d,sd);  d = e0.w-c0.w; sd = fmaf(d,d,sd);
        }
        #pragma unroll
        for (int m = 0; m < 2; ++m) {
            float4 e0 = ev[2*m], e1 = ev[2*m+1];
            uint2 u;
            u.x = pk8(e0.x, e0.y, e0.z, e0.w);
            u.y = pk8(e1.x, e1.y, e1.z, e1.w);
            unsigned j = (unsigned)(q8 * 2 + m);          // slot 0..15
            *(uint2*)(sAb + (unsigned)r * 128u + ((8u * j) ^ swA)) = u;
        }
        se += __shfl_xor(se, 1); se += __shfl_xor(se, 2); se += __shfl_xor(se, 4);
        sd += __shfl_xor(sd, 1); sd += __shfl_xor(sd, 2); sd += __shfl_xor(sd, 4);
        if (q8 == 0) sRT[r] = 0.5f * (1.0f + sd - se);
    }
    __syncthreads();   // the ONLY barrier before the reduction

    // hoist A fragments: row = 16*mf + li; k = 8*lh + 32*ks + e
    i64 aF[2][4];
    #pragma unroll
    for (int mf = 0; mf < 2; ++mf)
        #pragma unroll
        for (int ks = 0; ks < 4; ++ks)
            aF[mf][ks] = *(const i64*)(sAb + (unsigned)(16*mf + li) * 128u +
                                       (((unsigned)(8*lh + 32*ks)) ^ sw));
    float rtv[8];
    #pragma unroll
    for (int mf = 0; mf < 2; ++mf)
        #pragma unroll
        for (int rr = 0; rr < 4; ++rr)
            rtv[mf*4+rr] = sRT[16*mf + 4*lh + rr];

    // per-lane B base: wave-fragment-ordered replica (coalesced dwordx4 per wave)
    const unsigned char* gB = wsBx + (unsigned)wc * 4096u + (unsigned)l * 16u;

    float tsum = 0.f;

    // ---- K-loop: barrier-free, unroll 1 (bounds register pressure / load-hoisting) ----
    #pragma unroll 1
    for (int nt = 0; nt < NTC; ++nt) {
        // csq for this tile (issued first, consumed in epilogue ~300cy later)
        const float cq0 = csqx[nt*128 + wc*32 + li];
        const float cq1 = csqx[nt*128 + wc*32 + 16 + li];

        i64 bF0[4], bF1[4];
        #pragma unroll
        for (int ks = 0; ks < 4; ++ks) {
            i64x2 v = *(const i64x2*)(gB + (unsigned)nt * 16384u + (unsigned)ks * 1024u);
            bF0[ks] = v.x;   // col wc*32 + li
            bF1[ks] = v.y;   // col wc*32 + 16 + li
        }

        // acc init = rt_half only; cq subtracted in epilogue (algebraically identical)
        f32x4 acc[2][2];
        #pragma unroll
        for (int mf = 0; mf < 2; ++mf)
            #pragma unroll
            for (int rr = 0; rr < 4; ++rr) {
                acc[mf][0][rr] = rtv[mf*4+rr];
                acc[mf][1][rr] = rtv[mf*4+rr];
            }

        #pragma unroll
        for (int ks = 0; ks < 4; ++ks)
            #pragma unroll
            for (int mf = 0; mf < 2; ++mf) {
                acc[mf][0] = __builtin_amdgcn_mfma_f32_16x16x32_fp8_fp8(aF[mf][ks], bF0[ks], acc[mf][0], 0, 0, 0);
                acc[mf][1] = __builtin_amdgcn_mfma_f32_16x16x32_fp8_fp8(aF[mf][ks], bF1[ks], acc[mf][1], 0, 0, 0);
            }

        float s0 = 0.f, s1 = 0.f;
        #pragma unroll
        for (int mf = 0; mf < 2; ++mf)
            #pragma unroll
            for (int rr = 0; rr < 4; ++rr) {
                s0 = fmaf(2.0f, fmaxf(acc[mf][0][rr] - cq0, 0.f), s0);
                s1 = fmaf(2.0f, fmaxf(acc[mf][1][rr] - cq1, 0.f), s1);
            }
        tsum += s0 + s1;
    }

    // ---- block reduction -> deterministic per-block partial ----
    float s = tsum;
    #pragma unroll
    for (int off = 32; off; off >>= 1) s += __shfl_down(s, off);
    if (l == 0) sRed[wc] = s;
    __syncthreads();
    if (t == 0) partials[blockIdx.x] = sRed[0] + sRed[1] + sRed[2] + sRed[3];
}

// ---------- final reduction ----------
__global__ void reduce_k(const float* __restrict__ partials, int n,
                         float* __restrict__ out, double diagSub, double invDenom) {
    __shared__ double sRed[4];
    int t = threadIdx.x;
    double s = 0.0;
    for (int i = t; i < n; i += 256) s += (double)partials[i];
    #pragma unroll
    for (int off = 32; off; off >>= 1) s += __shfl_down(s, off);
    if ((t & 63) == 0) sRed[t >> 6] = s;
    __syncthreads();
    if (t == 0) out[0] = (float)(((sRed[0]+sRed[1]+sRed[2]+sRed[3]) - diagSub) * invDenom);
}

extern "C" void kernel_launch(void* const* d_in, const int* in_sizes, int n_in,
                              void* d_out, int out_size, void* d_ws, size_t ws_size,
                              hipStream_t stream) {
    const float* emb = (const float*)d_in[0];
    const int*   tgt = (const int*)d_in[1];
    const float* ctr = (const float*)d_in[2];

    const int B = in_sizes[1];                 // 32768
    const int C = in_sizes[2] / DD;            // 1000
    const int Cpad = NTC * 128;                // 1024
    const int nblk = B / BM;                   // 1024 = 4 blocks/CU

    unsigned char* wsB = (unsigned char*)d_ws;                        // 8 x 128 KB replicas
    float* csqh = (float*)(wsB + (size_t)NCOPY * COPYBYTES);          // 8 x 1024
    float* partials = csqh + NCOPY * 1024;                            // [nblk]

    prep_centers<<<(Cpad * 16) / 256, 256, 0, stream>>>(ctr, wsB, csqh, C, Cpad);
    center_mfma<<<nblk, 256, 0, stream>>>(emb, tgt, ctr, wsB, csqh, partials);
    reduce_k<<<1, 256, 0, stream>>>(partials, nblk, (float*)d_out,
                                    (double)B,
                                    1.0 / ((double)B * (double)(C - 1)));
}